// Round 22
// baseline (208.113 us; speedup 1.0000x reference)
//
#include <hip/hip_runtime.h>
#include <hip/hip_bf16.h>
#include <stdint.h>

typedef unsigned short u16;
typedef __attribute__((ext_vector_type(8))) short s16x8;   // 8 bf16 (4 VGPRs) — MFMA A/B frag
typedef __attribute__((ext_vector_type(4))) float f32x4;   // MFMA C/D frag

#define B_   2
#define T_   2048
#define D_   1024
#define H_   16
#define HD_  64
#define DFF_ 4096
#define M_   (B_*T_)   // 4096

#define SC2F 0.18033688f   // (1/8) * log2(e) — folded into Q at QKV epilogue

// ---------- helpers ----------
__device__ __forceinline__ u16 f2b(float f){          // fp32 -> bf16, RNE
  uint32_t u = __float_as_uint(f);
  u += 0x7FFFu + ((u >> 16) & 1u);
  return (u16)(u >> 16);
}
__device__ __forceinline__ float b2f(u16 u){ return __uint_as_float(((uint32_t)u) << 16); }
__device__ __forceinline__ uint32_t pk2(float lo, float hi){  // 2xf32 -> packed 2xbf16
  uint32_t r;
  asm volatile("v_cvt_pk_bf16_f32 %0, %1, %2" : "=v"(r) : "v"(lo), "v"(hi));
  return r;
}

// async global->LDS, 16B per lane. LDS dest is wave-uniform-base + lane*16 (lane-linear).
__device__ __forceinline__ void gl_lds16(const void* g, void* l){
  __builtin_amdgcn_global_load_lds((const __attribute__((address_space(1))) void*)g,
                                   (__attribute__((address_space(3))) void*)l, 16, 0, 0);
}

template<int N> __device__ __forceinline__ void waitvm(){
  if constexpr (N == 0)      asm volatile("s_waitcnt vmcnt(0)" ::: "memory");
  else if constexpr (N == 2) asm volatile("s_waitcnt vmcnt(2)" ::: "memory");
  else if constexpr (N == 4) asm volatile("s_waitcnt vmcnt(4)" ::: "memory");
  else                       asm volatile("s_waitcnt vmcnt(8)" ::: "memory");
}

// ---------- shared wconv tile body: one 64x64 tile fp32[K][N] -> bf16[N][K] ----------
__device__ __forceinline__ void wconv_tile(const float* __restrict__ W, u16* __restrict__ Wt,
                                           int K, int N, int tk, int tn, int tid,
                                           u16* __restrict__ tile /* 64*68 */){
  const int k0 = tk << 6, n0 = tn << 6;
  const int rr = tid >> 4, c4 = (tid & 15) << 2;
  #pragma unroll
  for (int rep = 0; rep < 4; rep++){
    int r = rr + (rep << 4);
    float4 v = *reinterpret_cast<const float4*>(W + (size_t)(k0 + r)*N + n0 + c4);
    tile[r*68 + c4+0] = f2b(v.x); tile[r*68 + c4+1] = f2b(v.y);
    tile[r*68 + c4+2] = f2b(v.z); tile[r*68 + c4+3] = f2b(v.w);
  }
  __syncthreads();
  const int rn = tid >> 2, kb = (tid & 3) << 4;
  u16 tmp[16];
  #pragma unroll
  for (int j = 0; j < 16; j++) tmp[j] = tile[(kb + j)*68 + rn];
  ushort4* dst = reinterpret_cast<ushort4*>(Wt + (size_t)(n0 + rn)*K + k0 + kb);
  dst[0] = make_ushort4(tmp[0], tmp[1], tmp[2], tmp[3]);
  dst[1] = make_ushort4(tmp[4], tmp[5], tmp[6], tmp[7]);
  dst[2] = make_ushort4(tmp[8], tmp[9], tmp[10], tmp[11]);
  dst[3] = make_ushort4(tmp[12], tmp[13], tmp[14], tmp[15]);
}

// ---------- wconv (wq/wk/wv/wo only) + LayerNorm1, one launch ----------
__global__ __launch_bounds__(256) void wconv_all(const float* __restrict__ wq,
                                                 const float* __restrict__ wk,
                                                 const float* __restrict__ wv,
                                                 const float* __restrict__ wo,
                                                 u16* __restrict__ wqkvT, u16* __restrict__ woT,
                                                 const float* __restrict__ x,
                                                 const float* __restrict__ ln1s,
                                                 const float* __restrict__ ln1b,
                                                 u16* __restrict__ hout){
  const int bid = blockIdx.x;
  const int tid = threadIdx.x;
  if (bid >= 1024){                                  // ---- LayerNorm1 rows ----
    const int row = bid - 1024;
    float4 a = reinterpret_cast<const float4*>(x + ((size_t)row << 10))[tid];
    float s = a.x + a.y + a.z + a.w;
    float q = a.x*a.x + a.y*a.y + a.z*a.z + a.w*a.w;
    #pragma unroll
    for (int o = 32; o > 0; o >>= 1){ s += __shfl_xor(s, o); q += __shfl_xor(q, o); }
    __shared__ float red[8];
    const int w = tid >> 6;
    if ((tid & 63) == 0){ red[w] = s; red[4 + w] = q; }
    __syncthreads();
    float S = red[0] + red[1] + red[2] + red[3];
    float Q = red[4] + red[5] + red[6] + red[7];
    float mean = S * (1.0f/1024.0f);
    float var  = Q * (1.0f/1024.0f) - mean*mean;
    float inv = rsqrtf(var + 1e-5f);
    float4 gsc = reinterpret_cast<const float4*>(ln1s)[tid];
    float4 gsh = reinterpret_cast<const float4*>(ln1b)[tid];
    ushort4 o4;
    o4.x = f2b((a.x - mean)*inv*gsc.x + gsh.x);
    o4.y = f2b((a.y - mean)*inv*gsc.y + gsh.y);
    o4.z = f2b((a.z - mean)*inv*gsc.z + gsh.z);
    o4.w = f2b((a.w - mean)*inv*gsc.w + gsh.w);
    reinterpret_cast<ushort4*>(hout + ((size_t)row << 10))[tid] = o4;
    return;
  }
  __shared__ u16 tile[64*68];
  const int which = bid >> 8, t = bid & 255;
  const float* W = (which == 0) ? wq : (which == 1) ? wk : (which == 2) ? wv : wo;
  u16* Wt = (which == 3) ? woT : wqkvT + (size_t)which * D_ * D_;
  wconv_tile(W, Wt, 1024, 1024, t >> 4, t & 15, tid, tile);
}

// ---------- split-K reduce (bf16 partials, +bias, + bf16 resid) -> fp32 out ----------
__global__ __launch_bounds__(256) void reduce2(const u16* __restrict__ p,
                                               const float* __restrict__ bias,
                                               const u16* __restrict__ resid,
                                               float* __restrict__ out){
  const size_t idx = ((size_t)blockIdx.x << 8) + threadIdx.x;      // 4-elem index
  ushort4 a4 = reinterpret_cast<const ushort4*>(p)[idx];
  ushort4 b4 = reinterpret_cast<const ushort4*>(p)[idx + (((size_t)M_*D_) >> 2)];
  ushort4 r4 = reinterpret_cast<const ushort4*>(resid)[idx];
  float4 bb = reinterpret_cast<const float4*>(bias)[threadIdx.x];
  float4 o;
  o.x = b2f(a4.x) + b2f(b4.x) + b2f(r4.x) + bb.x;
  o.y = b2f(a4.y) + b2f(b4.y) + b2f(r4.y) + bb.y;
  o.z = b2f(a4.z) + b2f(b4.z) + b2f(r4.z) + bb.z;
  o.w = b2f(a4.w) + b2f(b4.w) + b2f(r4.w) + bb.w;
  reinterpret_cast<float4*>(out)[idx] = o;
}

// ---------- fused: split-K reduce (+bo + fp32 resid x) -> x1 bf16 AND LN2 -> h2 bf16 ----------
__global__ __launch_bounds__(256) void reduce_ln(const u16* __restrict__ p,
                                                 const float* __restrict__ bias,
                                                 const float* __restrict__ resid,
                                                 const float* __restrict__ sc,
                                                 const float* __restrict__ sh,
                                                 u16* __restrict__ x1,
                                                 u16* __restrict__ h2){
  const int row = blockIdx.x;
  const int tid = threadIdx.x;
  const size_t idx = ((size_t)row << 8) + tid;
  ushort4 a4 = reinterpret_cast<const ushort4*>(p)[idx];
  ushort4 b4 = reinterpret_cast<const ushort4*>(p)[idx + (((size_t)M_*D_) >> 2)];
  float4 r  = reinterpret_cast<const float4*>(resid)[idx];
  float4 bb = reinterpret_cast<const float4*>(bias)[tid];
  float4 v;
  v.x = b2f(a4.x) + b2f(b4.x) + r.x + bb.x;
  v.y = b2f(a4.y) + b2f(b4.y) + r.y + bb.y;
  v.z = b2f(a4.z) + b2f(b4.z) + r.z + bb.z;
  v.w = b2f(a4.w) + b2f(b4.w) + r.w + bb.w;
  ushort4 xo;
  xo.x = f2b(v.x); xo.y = f2b(v.y); xo.z = f2b(v.z); xo.w = f2b(v.w);
  reinterpret_cast<ushort4*>(x1)[idx] = xo;
  float s = v.x + v.y + v.z + v.w;
  float q = v.x*v.x + v.y*v.y + v.z*v.z + v.w*v.w;
  #pragma unroll
  for (int o = 32; o > 0; o >>= 1){ s += __shfl_xor(s, o); q += __shfl_xor(q, o); }
  __shared__ float red[8];
  const int w = tid >> 6;
  if ((tid & 63) == 0){ red[w] = s; red[4 + w] = q; }
  __syncthreads();
  float S = red[0] + red[1] + red[2] + red[3];
  float Q = red[4] + red[5] + red[6] + red[7];
  float mean = S * (1.0f/1024.0f);
  float var  = Q * (1.0f/1024.0f) - mean*mean;
  float inv = rsqrtf(var + 1e-5f);
  float4 gsc = reinterpret_cast<const float4*>(sc)[tid];
  float4 gsh = reinterpret_cast<const float4*>(sh)[tid];
  ushort4 o4;
  o4.x = f2b((v.x - mean)*inv*gsc.x + gsh.x);
  o4.y = f2b((v.y - mean)*inv*gsc.y + gsh.y);
  o4.z = f2b((v.z - mean)*inv*gsc.z + gsh.z);
  o4.w = f2b((v.w - mean)*inv*gsc.w + gsh.w);
  reinterpret_cast<ushort4*>(h2 + ((size_t)row << 10))[tid] = o4;
}

// ---------- 4-merged-phase 256-wide bf16 GEMM (32 MFMA per barrier) — r21 best ----------
template<int EPI, int NF>
__global__ __launch_bounds__(512, 2) void gemm8(const u16* __restrict__ A, const u16* __restrict__ Bt,
                                                const float* __restrict__ bias,
                                                void* __restrict__ Cv, void* __restrict__ Cv2,
                                                const float* __restrict__ cw1,
                                                const float* __restrict__ cw2,
                                                u16* __restrict__ w1T, u16* __restrict__ w2T,
                                                int M, int N, int K, int lda){
  constexpr int BROWS = NF * 32;            // rows per B half-tile
  __shared__ __align__(16) u16 LA[2][2][128*64];
  __shared__ __align__(16) u16 LB[2][2][BROWS*64];
  const int tid = threadIdx.x;

  if constexpr (EPI == 1){
    if (blockIdx.x >= 192){                 // ---- w1/w2 conversion filler blocks ----
      const int tid256 = tid & 255, sel2 = tid >> 8;
      u16* tile = &LA[0][0][0] + sel2 * (64*68);
      const int t = ((int)blockIdx.x - 192)*2 + sel2;
      if (t < 1024) wconv_tile(cw1, w1T, 1024, 4096, t >> 6, t & 63, tid256, tile);
      else          wconv_tile(cw2, w2T, 4096, 1024, (t-1024) >> 4, (t-1024) & 15, tid256, tile);
      return;
    }
  }

  const int lane = tid & 63;
  const int w = tid >> 6;
  const int wm = w >> 2, wn = w & 3;
  const int g = lane >> 4, l15 = lane & 15;
  const int bnb = (wn & 1) * (NF * 16);     // B local row base within half (wn>>1)

  int tn, tm, kz;
  if constexpr (EPI == 1){                  // 1D grid, 192 gemm blocks
    const int flat = blockIdx.x;
    const int nfid = (flat & 7) * 24 + (flat >> 3);
    tn = nfid % 12; tm = nfid / 12; kz = 0;
  } else {
    const int nx = gridDim.x, ny = gridDim.y;
    const int nwg = nx * ny * gridDim.z;
    const int flat = blockIdx.x + nx * (blockIdx.y + ny * blockIdx.z);
    const int nfid = (flat & 7) * (nwg >> 3) + (flat >> 3);
    tn = nfid % nx;
    const int rest = nfid / nx;
    tm = rest % ny;
    kz = rest / ny;
  }
  const int tn0 = tn * (NF * 64);
  const int tm0 = tm << 8;
  const u16* Az = A  + (size_t)kz * K;
  const u16* Bz = Bt + (size_t)kz * K;

  const int arow0 = tid >> 3,         asl0 = (((tid) & 7) ^ (arow0 & 7)) << 3;
  const int arow1 = (tid + 512) >> 3, asl1 = (((tid + 512) & 7) ^ (arow1 & 7)) << 3;

  f32x4 acc[8][NF];
  #pragma unroll
  for (int i = 0; i < 8; i++)
    #pragma unroll
    for (int j = 0; j < NF; j++) acc[i][j] = (f32x4){0.f,0.f,0.f,0.f};
  s16x8 bf[NF][2];
  constexpr int WVX = (NF == 4) ? 8 : 2;    // relaxed exact-sufficiency (r21 ledger)

#define STG_A(db, h, tt) do{                                                        \
    gl_lds16(Az + (size_t)(tm0 + (h)*128 + arow0)*lda + ((tt) << 6) + asl0,         \
             &LA[db][h][tid*8]);                                                    \
    gl_lds16(Az + (size_t)(tm0 + (h)*128 + arow1)*lda + ((tt) << 6) + asl1,         \
             &LA[db][h][(tid + 512)*8]);                                            \
  }while(0)
#define STG_B(db, h, tt) do{                                                        \
    gl_lds16(Bz + (size_t)(tn0 + (h)*BROWS + arow0)*lda + ((tt) << 6) + asl0,       \
             &LB[db][h][tid*8]);                                                    \
    if constexpr (NF == 4){                                                         \
      gl_lds16(Bz + (size_t)(tn0 + (h)*BROWS + arow1)*lda + ((tt) << 6) + asl1,     \
               &LB[db][h][(tid + 512)*8]);                                          \
    }                                                                               \
  }while(0)
#define LDAF(db, mf, kk) (*reinterpret_cast<const s16x8*>(                          \
    &LA[db][wm][((mf)*16 + l15)*64 + ((((kk)*4 + g) ^ (l15 & 7)) << 3)]))
#define LDBF(db, nf, kk) (*reinterpret_cast<const s16x8*>(                          \
    &LB[db][wn >> 1][(bnb + (nf)*16 + l15)*64 + ((((kk)*4 + g) ^ (l15 & 7)) << 3)]))
#define BLOAD(db) do{ _Pragma("unroll")                                             \
    for (int nf = 0; nf < NF; nf++){ bf[nf][0] = LDBF(db, nf, 0);                   \
                                     bf[nf][1] = LDBF(db, nf, 1); } }while(0)
#define PH2(db, MF0, STG, WV) do{                                                   \
    s16x8 aA0 = LDAF(db, (MF0)+0, 0), aA1 = LDAF(db, (MF0)+0, 1);                   \
    s16x8 aB0 = LDAF(db, (MF0)+1, 0), aB1 = LDAF(db, (MF0)+1, 1);                   \
    s16x8 aC0 = LDAF(db, (MF0)+2, 0), aC1 = LDAF(db, (MF0)+2, 1);                   \
    s16x8 aD0 = LDAF(db, (MF0)+3, 0), aD1 = LDAF(db, (MF0)+3, 1);                   \
    STG;                                                                            \
    WV;                                                                             \
    __builtin_amdgcn_s_barrier();                                                   \
    __builtin_amdgcn_s_setprio(1);                                                  \
    _Pragma("unroll")                                                               \
    for (int nf = 0; nf < NF; nf++){                                                \
      acc[(MF0)+0][nf] = __builtin_amdgcn_mfma_f32_16x16x32_bf16(aA0, bf[nf][0], acc[(MF0)+0][nf], 0,0,0); \
      acc[(MF0)+0][nf] = __builtin_amdgcn_mfma_f32_16x16x32_bf16(aA1, bf[nf][1], acc[(MF0)+0][nf], 0,0,0); \
      acc[(MF0)+1][nf] = __builtin_amdgcn_mfma_f32_16x16x32_bf16(aB0, bf[nf][0], acc[(MF0)+1][nf], 0,0,0); \
      acc[(MF0)+1][nf] = __builtin_amdgcn_mfma_f32_16x16x32_bf16(aB1, bf[nf][1], acc[(MF0)+1][nf], 0,0,0); \
      acc[(MF0)+2][nf] = __builtin_amdgcn_mfma_f32_16x16x32_bf16(aC0, bf[nf][0], acc[(MF0)+2][nf], 0,0,0); \
      acc[(MF0)+2][nf] = __builtin_amdgcn_mfma_f32_16x16x32_bf16(aC1, bf[nf][1], acc[(MF0)+2][nf], 0,0,0); \
      acc[(MF0)+3][nf] = __builtin_amdgcn_mfma_f32_16x16x32_bf16(aD0, bf[nf][0], acc[(MF0)+3][nf], 0,0,0); \
      acc[(MF0)+3][nf] = __builtin_amdgcn_mfma_f32_16x16x32_bf16(aD1, bf[nf][1], acc[(MF0)+3][nf], 0,0,0); \
    }                                                                               \
    __builtin_amdgcn_s_setprio(0);                                                  \
    __builtin_amdgcn_s_barrier();                                                   \
  }while(0)

  const int NT = K >> 6;                     // even at every call site
  STG_B(0, 0, 0); STG_B(0, 1, 0); STG_A(0, 0, 0); STG_A(0, 1, 0);
  STG_B(1, 0, 1); STG_B(1, 1, 1);
  waitvm<WVX>();
  __builtin_amdgcn_s_barrier();

  for (int t = 0; t < NT; t += 2){
    const bool last = (t + 2 >= NT);
    BLOAD(0);
    PH2(0, 0, { STG_A(1, 0, t + 1); STG_A(1, 1, t + 1); }, );
    PH2(0, 4, { if (!last){ STG_B(0, 0, t + 2); STG_B(0, 1, t + 2); } },
              if (last) waitvm<0>(); else waitvm<WVX>(););
    BLOAD(1);
    PH2(1, 0, { if (!last){ STG_A(0, 0, t + 2); STG_A(0, 1, t + 2); } }, );
    PH2(1, 4, { if (!last){ STG_B(1, 0, t + 3); STG_B(1, 1, t + 3); } },
              if (last) waitvm<0>(); else waitvm<WVX>(););
  }
#undef STG_A
#undef STG_B
#undef LDAF
#undef LDBF
#undef BLOAD
#undef PH2

  if constexpr (EPI == 1){
    const int sel = tn0 >> 10;                     // block-uniform: 256-col tiles
    if (sel < 2){                                  // ---- Q/K coalesced scatter ----
      #pragma unroll
      for (int mf = 0; mf < 8; mf++){
        const int mb = tm0 + wm*128 + mf*16 + (g << 2);
        #pragma unroll
        for (int nf = 0; nf < NF; nf++){
          const int n = tn0 + wn*(NF*16) + nf*16 + l15;
          const int nn = n & 1023;
          const int hh = nn >> 6, d = nn & 63;
          #pragma unroll
          for (int rr = 0; rr < 4; rr++){
            const int m = mb + rr;
            float v = acc[mf][nf][rr];
            if (sel == 0) v *= SC2F;
            ((u16*)Cv)[(size_t)sel*((size_t)M_*D_) +
                       ((((size_t)(m >> 11)*H_ + hh)*T_ + (m & 2047)) << 6) + d] = f2b(v);
          }
        }
      }
    } else {                                       // ---- V: LDS transpose -> V^T [B][H][HD][T] ----
      u16* TR = &LA[0][0][0];                      // 128 x 256 u16 view (64KB), XOR-swizzled
      u16* vt = (u16*)Cv2;
      const int bq = tm0 >> 11;                    // batch index
      const int tloc = tm0 & 2047;                 // within-batch t base
      #pragma unroll
      for (int hp = 0; hp < 2; hp++){
        __syncthreads();                           // prev LA use / prev hp reads done
        if ((wn >> 1) == hp){
          #pragma unroll
          for (int mf = 0; mf < 8; mf++){
            const int mb = wm*128 + mf*16 + (g << 2);
            #pragma unroll
            for (int nf = 0; nf < NF; nf++){
              const int nr = ((wn & 1) << 6) + (nf << 4) + l15;    // [0,128)
              #pragma unroll
              for (int rr = 0; rr < 4; rr++){
                const int m = mb + rr;
                TR[nr*256 + (((m >> 3) ^ (nr & 15)) << 3) + (m & 7)] = f2b(acc[mf][nf][rr]);
              }
            }
          }
        }
        __syncthreads();
        {
          const int nr = tid >> 2;                 // [0,128)
          const int m0 = (tid & 3) << 6;           // 64-elem run per thread
          const int nn = (tn0 & 1023) + (hp << 7) + nr;
          const int hh = nn >> 6, d = nn & 63;
          u16* dst = vt + (((size_t)(bq*H_ + hh))*HD_ + d)*T_ + tloc + m0;
          #pragma unroll
          for (int jj = 0; jj < 8; jj++){
            const int j = (m0 >> 3) + jj;
            s16x8 vv = *reinterpret_cast<const s16x8*>(&TR[nr*256 + ((j ^ (nr & 15)) << 3)]);
            *reinterpret_cast<s16x8*>(dst + jj*8) = vv;
          }
        }
      }
    }
  } else {
    #pragma unroll
    for (int mf = 0; mf < 8; mf++){
      const int mb = tm0 + wm*128 + mf*16 + (g << 2);
      #pragma unroll
      for (int nf = 0; nf < NF; nf++){
        const int n = tn0 + wn*(NF*16) + nf*16 + l15;
        #pragma unroll
        for (int rr = 0; rr < 4; rr++){
          const int m = mb + rr;
          float v = acc[mf][nf][rr];
          if constexpr (EPI == 0){
            ((u16*)Cv)[(size_t)kz*((size_t)M*N) + (size_t)m*N + n] = f2b(v);
          } else {
            float u = v + bias[n];
            float t2 = 0.7978845608f*(u + 0.044715f*u*u*u);
            float e = __expf(2.0f*t2);
            float th = 1.0f - 2.0f/(e + 1.0f);
            ((u16*)Cv)[(size_t)m*N + n] = f2b(0.5f*u*(1.0f + th));
          }
        }
      }
    }
  }
}

// ---------- causal flash attention, v13: T15 pipeline (QK^T(kt+1) MFMA ∥ softmax(kt) VALU) ----------
// Ks 3-deep (prefetch distance 2), Vt 2-deep, double accS (named accA/accB, 2-unrolled).
// LDS 128KB: Qs 16 + Ks 48 + Vt 32 + Pl 32. One __syncthreads per k-iter (drains prefetches).
__global__ __launch_bounds__(512) void attn_k(const u16* __restrict__ Qg, const u16* __restrict__ Kg,
                                              const u16* __restrict__ Vg, u16* __restrict__ ctx){
  const int flat = blockIdx.x + (blockIdx.y << 3);
  const int xcd = flat & 7, j_ = (flat >> 3) & 3, pr_ = flat >> 5;   // pr_ in [0,8)
  const int bh  = (j_ << 3) + xcd;
  const int tid = threadIdx.x;
  const int lane = tid & 63;
  const int w = tid >> 6;                         // 0..7, wave owns q rows [16w,16w+16)
  const int g = lane >> 4, l15 = lane & 15;

  __shared__ __align__(16) u16 Qs[128*64];
  __shared__ __align__(16) u16 Ks[3][128*64];     // [krow][d], prefetch distance 2
  __shared__ __align__(16) u16 Vt[2][64*128];     // [d][t]
  __shared__ __align__(16) u16 Pl[8][16*128];     // per-wave P [q][k]
  u16* const Plw = &Pl[w][0];
  u16* const Ks0 = &Ks[0][0];

  const size_t hb = (size_t)bh * ((size_t)T_*HD_);
  const u16* Qh = Qg + hb;
  const u16* Kh = Kg + hb;
  const u16* Vh = Vg + hb;                        // transposed head: [64][2048]
  const int b = bh >> 4, hh = bh & 15;

  const int qk_r0 = tid >> 3,         qk_c0 = (((tid) & 7) ^ (qk_r0 & 7)) << 3;
  const int qk_r1 = (tid + 512) >> 3, qk_c1 = (((tid + 512) & 7) ^ (qk_r1 & 7)) << 3;
  const int v_r0 = tid >> 4,          v_c0 = (((tid) & 15) ^ (v_r0 & 7)) << 3;
  const int v_r1 = (tid + 512) >> 4,  v_c1 = (((tid + 512) & 15) ^ (v_r1 & 7)) << 3;

#define QKT_INTO(DST, KBUF) do{                                                    \
    _Pragma("unroll")                                                              \
    for (int j = 0; j < 8; j++) DST[j] = (f32x4){0.f,0.f,0.f,0.f};                 \
    __builtin_amdgcn_s_setprio(1);                                                 \
    _Pragma("unroll")                                                              \
    for (int jn = 0; jn < 8; jn++){                                                \
      _Pragma("unroll")                                                            \
      for (int kk = 0; kk < 2; kk++){                                              \
        int rb = (jn << 4) + l15;                                                  \
        int slot = (kk << 2) + g;                                                  \
        s16x8 kf = *reinterpret_cast<const s16x8*>((KBUF) + rb*64 + ((slot ^ (rb & 7)) << 3)); \
        DST[jn] = __builtin_amdgcn_mfma_f32_16x16x32_bf16(kf, qa[kk], DST[jn], 0, 0, 0); \
      }                                                                            \
    }                                                                              \
    __builtin_amdgcn_s_setprio(0);                                                 \
  }while(0)

// STEP: prefetch K(kt+2)/V(kt+1); QK^T(kt+1)->NXT (overlaps softmax below); softmax+PV(kt) on CUR.
#define STEP(KT, CUR, NXT) do{                                                     \
    const int kt_ = (KT);                                                          \
    const int vcur_ = kt_ & 1, vnxt_ = vcur_ ^ 1;                                  \
    const bool hn_ = (kt_ + 1 < NKT);                                              \
    if (kt_ + 2 < NKT){                                                            \
      u16* kb2 = Ks0 + ((kt_ + 2) % 3) * (128*64);                                 \
      gl_lds16(Kh + (size_t)((kt_+2)*128 + qk_r0)*HD_ + qk_c0, kb2 + tid*8);       \
      gl_lds16(Kh + (size_t)((kt_+2)*128 + qk_r1)*HD_ + qk_c1, kb2 + (tid+512)*8); \
    }                                                                              \
    if (hn_){                                                                      \
      gl_lds16(Vh + (size_t)v_r0*T_ + (kt_+1)*128 + v_c0, Vt[vnxt_] + tid*8);      \
      gl_lds16(Vh + (size_t)v_r1*T_ + (kt_+1)*128 + v_c1, Vt[vnxt_] + (tid+512)*8);\
      const u16* kb1 = Ks0 + ((kt_ + 1) % 3) * (128*64);                           \
      QKT_INTO(NXT, kb1);                                                          \
    }                                                                              \
    /* ---- softmax(kt) on CUR ---- */                                             \
    if (kt_ == qt){                                                                \
      _Pragma("unroll")                                                            \
      for (int jn = 0; jn < 8; jn++)                                               \
        _Pragma("unroll")                                                          \
        for (int rr = 0; rr < 4; rr++){                                            \
          int kgl = kt_*128 + (jn << 4) + (g << 2) + rr;                           \
          if (kgl > qgl) CUR[jn][rr] = -1e30f;                                     \
        }                                                                          \
    }                                                                              \
    float rmax = CUR[0][0];                                                        \
    _Pragma("unroll")                                                              \
    for (int jn = 0; jn < 8; jn++)                                                 \
      _Pragma("unroll")                                                            \
      for (int rr = 0; rr < 4; rr++) rmax = fmaxf(rmax, CUR[jn][rr]);              \
    rmax = fmaxf(rmax, __shfl_xor(rmax, 16));                                      \
    rmax = fmaxf(rmax, __shfl_xor(rmax, 32));                                      \
    if (__any(rmax > mrow + 8.0f)){                                                \
      float mn = fmaxf(mrow, rmax);                                                \
      float sf = exp2f(mrow - mn);                                                 \
      mrow = mn;                                                                   \
      lrow *= sf;                                                                  \
      _Pragma("unroll")                                                            \
      for (int rr = 0; rr < 4; rr++){                                              \
        float sfr = __shfl(sf, ((lane >> 4) << 2) + rr);                           \
        _Pragma("unroll")                                                          \
        for (int jn = 0; jn < 4; jn++) accO[jn][rr] *= sfr;                        \
      }                                                                            \
    }                                                                              \
    float tsum = 0.f;                                                              \
    _Pragma("unroll")                                                              \
    for (int jn = 0; jn < 8; jn++){                                                \
      float pv0 = exp2f(CUR[jn][0] - mrow);                                        \
      float pv1 = exp2f(CUR[jn][1] - mrow);                                        \
      float pv2 = exp2f(CUR[jn][2] - mrow);                                        \
      float pv3 = exp2f(CUR[jn][3] - mrow);                                        \
      tsum += (pv0 + pv1) + (pv2 + pv3);                                           \
      int ch = ((jn << 1) | (g >> 1)) ^ (l15 & 7);                                 \
      int base = (l15 << 7) + (ch << 3) + ((g & 1) << 2);                          \
      uint2 pkd = make_uint2(pk2(pv0, pv1), pk2(pv2, pv3));                        \
      *reinterpret_cast<uint2*>(&Plw[base]) = pkd;                                 \
    }                                                                              \
    tsum += __shfl_xor(tsum, 16);                                                  \
    tsum += __shfl_xor(tsum, 32);                                                  \
    lrow += tsum;                                                                  \
    /* ---- O += P V from Vt[vcur_] ---- */                                        \
    __builtin_amdgcn_s_setprio(1);                                                 \
    _Pragma("unroll")                                                              \
    for (int kk = 0; kk < 4; kk++){                                                \
      int pch = ((kk << 2) + g) ^ (l15 & 7);                                       \
      s16x8 pa = *reinterpret_cast<const s16x8*>(&Plw[(l15 << 7) + (pch << 3)]);   \
      _Pragma("unroll")                                                            \
      for (int jn = 0; jn < 4; jn++){                                              \
        int vd = (jn << 4) + l15;                                                  \
        int vslot = (((kk << 2) + g) & 8) | ((((kk << 2) + g) ^ (vd & 7)) & 7);    \
        s16x8 vbf = *reinterpret_cast<const s16x8*>(Vt[vcur_] + (vd << 7) + (vslot << 3)); \
        accO[jn] = __builtin_amdgcn_mfma_f32_16x16x32_bf16(pa, vbf, accO[jn], 0, 0, 0); \
      }                                                                            \
    }                                                                              \
    __builtin_amdgcn_s_setprio(0);                                                 \
    __syncthreads();                                                               \
  }while(0)

  for (int ph = 0; ph < 2; ++ph){
    const int qt = ph ? (15 - pr_) : pr_;
    const int NKT = qt + 1;

    gl_lds16(Qh + (size_t)(qt*128 + qk_r0)*HD_ + qk_c0, Qs + tid*8);
    gl_lds16(Qh + (size_t)(qt*128 + qk_r1)*HD_ + qk_c1, Qs + (tid+512)*8);
    gl_lds16(Kh + (size_t)qk_r0*HD_ + qk_c0, Ks[0] + tid*8);
    gl_lds16(Kh + (size_t)qk_r1*HD_ + qk_c1, Ks[0] + (tid+512)*8);
    if (NKT > 1){
      gl_lds16(Kh + (size_t)(128 + qk_r0)*HD_ + qk_c0, Ks[1] + tid*8);
      gl_lds16(Kh + (size_t)(128 + qk_r1)*HD_ + qk_c1, Ks[1] + (tid+512)*8);
    }
    gl_lds16(Vh + (size_t)v_r0*T_ + v_c0, Vt[0] + tid*8);
    gl_lds16(Vh + (size_t)v_r1*T_ + v_c1, Vt[0] + (tid+512)*8);
    __syncthreads();

    s16x8 qa[2];
    #pragma unroll
    for (int kk = 0; kk < 2; kk++){
      int ra = (w << 4) + l15;
      int slot = (kk << 2) + g;
      qa[kk] = *reinterpret_cast<const s16x8*>(Qs + ra*64 + ((slot ^ (ra & 7)) << 3));
    }

    f32x4 accO[4];
    #pragma unroll
    for (int j = 0; j < 4; j++) accO[j] = (f32x4){0.f,0.f,0.f,0.f};
    float mrow = -1e30f, lrow = 0.f;
    const int qgl = qt*128 + (w << 4) + l15;      // this thread's global q row

    f32x4 accA[8], accB[8];
    QKT_INTO(accA, Ks0);                          // QK^T(0) — K0 resident after prologue sync

    int kt = 0;
    while (true){
      STEP(kt, accA, accB); kt++;
      if (kt >= NKT) break;
      STEP(kt, accB, accA); kt++;
      if (kt >= NKT) break;
    }

    // ---- epilogue: registers + global only (no LDS)
    #pragma unroll
    for (int rr = 0; rr < 4; rr++){
      float lr = __shfl(lrow, ((lane >> 4) << 2) + rr);
      float inv = 1.0f / lr;
      int qrow = qt*128 + (w << 4) + (g << 2) + rr;
      size_t rowbase = ((size_t)(b*T_ + qrow) << 10) + ((size_t)hh << 6);
      #pragma unroll
      for (int jn = 0; jn < 4; jn++){
        int d = (jn << 4) + l15;
        ctx[rowbase + d] = f2b(accO[jn][rr] * inv);
      }
    }
  }
#undef STEP
#undef QKT_INTO
}

// ---------- launch ----------
extern "C" void kernel_launch(void* const* d_in, const int* in_sizes, int n_in,
                              void* d_out, int out_size, void* d_ws, size_t ws_size,
                              hipStream_t stream){
  (void)in_sizes; (void)n_in; (void)out_size; (void)ws_size;
  const float* x    = (const float*)d_in[0];
  const float* wq   = (const float*)d_in[1];
  const float* wk   = (const float*)d_in[2];
  const float* wv   = (const float*)d_in[3];
  const float* wo   = (const float*)d_in[4];
  const float* bo   = (const float*)d_in[5];
  const float* ln1s = (const float*)d_in[6];
  const float* ln1b = (const float*)d_in[7];
  const float* ln2s = (const float*)d_in[8];
  const float* ln2b = (const float*)d_in[9];
  const float* w1   = (const float*)d_in[10];
  const float* b1   = (const float*)d_in[11];
  const float* w2   = (const float*)d_in[12];
  const float* b2   = (const float*)d_in[13];
  float* out = (float*)d_out;

  char* p = (char*)d_ws;
  u16*  wqkvT = (u16*)p;  p += (size_t)3*D_*D_*2;
  u16*  woT   = (u16*)p;  p += (size_t)D_*D_*2;
  u16*  w1T   = (u16*)p;  p += (size_t)D_*DFF_*2;
  u16*  w2T   = (u16*)p;  p += (size_t)DFF_*D_*2;
  u16*  h     = (u16*)p;  p += (size_t)M_*D_*2;   // ln1 out; later part of split-K buf
  u16*  qb    = (u16*)p;  p += (size_t)M_*D_*2;   // q | k ([2][B][H][T][HD])
  u16*  kb    = (u16*)p;  p += (size_t)M_*D_*2;
  u16*  vb    = (u16*)p;  p += (size_t)M_*D_*2;   // unused
  u16*  ctx   = (u16*)p;  p += (size_t)M_*D_*2;
  u16*  x1    = (u16*)p;  p += (size_t)M_*D_*2;   // bf16 residual stream
  u16*  h2    = (u16*)p;  p += (size_t)M_*D_*2;
  u16*  ff1   = (u16*)p;  p += (size_t)M_*DFF_*2; // V^T home during QKV..attn; FFN1 out after
  (void)kb; (void)vb;
  u16* part = h;   // bf16 partials [2][M][1024] = 16MB over h+qb (Q dead when written)

  dim3 blk(256), blk8(512);
  wconv_all<<<1024 + M_, blk, 0, stream>>>(wq, wk, wv, wo, wqkvT, woT, x, ln1s, ln1b, h);
  gemm8<1,4><<<192 + 1024, blk8, 0, stream>>>(h, wqkvT, nullptr, qb, ff1,
                                              w1, w2, w1T, w2T, M_, 3*D_, D_, D_);
  attn_k<<<dim3(8,32), blk8, 0, stream>>>(qb, qb + (size_t)M_*D_, ff1, ctx);
  gemm8<0,2><<<dim3(8,16,2), blk8, 0, stream>>>(ctx, woT, nullptr, part, nullptr,
                                                nullptr, nullptr, nullptr, nullptr,
                                                M_, D_, D_/2, D_);
  reduce_ln<<<M_, blk, 0, stream>>>(part, bo, x, ln2s, ln2b, x1, h2);
  gemm8<3,4><<<dim3(16,16,1), blk8, 0, stream>>>(h2, w1T, b1, ff1, nullptr,
                                                 nullptr, nullptr, nullptr, nullptr,
                                                 M_, DFF_, D_, D_);
  gemm8<0,2><<<dim3(8,16,2), blk8, 0, stream>>>(ff1, w2T, nullptr, part, nullptr,
                                                nullptr, nullptr, nullptr, nullptr,
                                                M_, D_, DFF_/2, DFF_);
  reduce2<<<M_, blk, 0, stream>>>(part, b2, x1, out);
}

// Round 23
// 202.795 us; speedup vs baseline: 1.0262x; 1.0262x over previous
//
#include <hip/hip_runtime.h>
#include <hip/hip_bf16.h>
#include <stdint.h>

typedef unsigned short u16;
typedef __attribute__((ext_vector_type(8))) short s16x8;   // 8 bf16 (4 VGPRs) — MFMA A/B frag
typedef __attribute__((ext_vector_type(4))) float f32x4;   // MFMA C/D frag

#define B_   2
#define T_   2048
#define D_   1024
#define H_   16
#define HD_  64
#define DFF_ 4096
#define M_   (B_*T_)   // 4096

#define SC2F 0.18033688f   // (1/8) * log2(e) — folded into Q at QKV epilogue

// ---------- helpers ----------
__device__ __forceinline__ u16 f2b(float f){          // fp32 -> bf16, RNE
  uint32_t u = __float_as_uint(f);
  u += 0x7FFFu + ((u >> 16) & 1u);
  return (u16)(u >> 16);
}
__device__ __forceinline__ float b2f(u16 u){ return __uint_as_float(((uint32_t)u) << 16); }
__device__ __forceinline__ uint32_t pk2(float lo, float hi){  // 2xf32 -> packed 2xbf16
  uint32_t r;
  asm volatile("v_cvt_pk_bf16_f32 %0, %1, %2" : "=v"(r) : "v"(lo), "v"(hi));
  return r;
}

// async global->LDS, 16B per lane. LDS dest is wave-uniform-base + lane*16 (lane-linear).
__device__ __forceinline__ void gl_lds16(const void* g, void* l){
  __builtin_amdgcn_global_load_lds((const __attribute__((address_space(1))) void*)g,
                                   (__attribute__((address_space(3))) void*)l, 16, 0, 0);
}

template<int N> __device__ __forceinline__ void waitvm(){
  if constexpr (N == 0)      asm volatile("s_waitcnt vmcnt(0)" ::: "memory");
  else if constexpr (N == 2) asm volatile("s_waitcnt vmcnt(2)" ::: "memory");
  else if constexpr (N == 4) asm volatile("s_waitcnt vmcnt(4)" ::: "memory");
  else                       asm volatile("s_waitcnt vmcnt(8)" ::: "memory");
}

// ---------- shared wconv tile body: one 64x64 tile fp32[K][N] -> bf16[N][K] ----------
__device__ __forceinline__ void wconv_tile(const float* __restrict__ W, u16* __restrict__ Wt,
                                           int K, int N, int tk, int tn, int tid,
                                           u16* __restrict__ tile /* 64*68 */){
  const int k0 = tk << 6, n0 = tn << 6;
  const int rr = tid >> 4, c4 = (tid & 15) << 2;
  #pragma unroll
  for (int rep = 0; rep < 4; rep++){
    int r = rr + (rep << 4);
    float4 v = *reinterpret_cast<const float4*>(W + (size_t)(k0 + r)*N + n0 + c4);
    tile[r*68 + c4+0] = f2b(v.x); tile[r*68 + c4+1] = f2b(v.y);
    tile[r*68 + c4+2] = f2b(v.z); tile[r*68 + c4+3] = f2b(v.w);
  }
  __syncthreads();
  const int rn = tid >> 2, kb = (tid & 3) << 4;
  u16 tmp[16];
  #pragma unroll
  for (int j = 0; j < 16; j++) tmp[j] = tile[(kb + j)*68 + rn];
  ushort4* dst = reinterpret_cast<ushort4*>(Wt + (size_t)(n0 + rn)*K + k0 + kb);
  dst[0] = make_ushort4(tmp[0], tmp[1], tmp[2], tmp[3]);
  dst[1] = make_ushort4(tmp[4], tmp[5], tmp[6], tmp[7]);
  dst[2] = make_ushort4(tmp[8], tmp[9], tmp[10], tmp[11]);
  dst[3] = make_ushort4(tmp[12], tmp[13], tmp[14], tmp[15]);
}

// ---------- wconv (wq/wk/wv/wo only) + LayerNorm1, one launch ----------
__global__ __launch_bounds__(256) void wconv_all(const float* __restrict__ wq,
                                                 const float* __restrict__ wk,
                                                 const float* __restrict__ wv,
                                                 const float* __restrict__ wo,
                                                 u16* __restrict__ wqkvT, u16* __restrict__ woT,
                                                 const float* __restrict__ x,
                                                 const float* __restrict__ ln1s,
                                                 const float* __restrict__ ln1b,
                                                 u16* __restrict__ hout){
  const int bid = blockIdx.x;
  const int tid = threadIdx.x;
  if (bid >= 1024){                                  // ---- LayerNorm1 rows ----
    const int row = bid - 1024;
    float4 a = reinterpret_cast<const float4*>(x + ((size_t)row << 10))[tid];
    float s = a.x + a.y + a.z + a.w;
    float q = a.x*a.x + a.y*a.y + a.z*a.z + a.w*a.w;
    #pragma unroll
    for (int o = 32; o > 0; o >>= 1){ s += __shfl_xor(s, o); q += __shfl_xor(q, o); }
    __shared__ float red[8];
    const int w = tid >> 6;
    if ((tid & 63) == 0){ red[w] = s; red[4 + w] = q; }
    __syncthreads();
    float S = red[0] + red[1] + red[2] + red[3];
    float Q = red[4] + red[5] + red[6] + red[7];
    float mean = S * (1.0f/1024.0f);
    float var  = Q * (1.0f/1024.0f) - mean*mean;
    float inv = rsqrtf(var + 1e-5f);
    float4 gsc = reinterpret_cast<const float4*>(ln1s)[tid];
    float4 gsh = reinterpret_cast<const float4*>(ln1b)[tid];
    ushort4 o4;
    o4.x = f2b((a.x - mean)*inv*gsc.x + gsh.x);
    o4.y = f2b((a.y - mean)*inv*gsc.y + gsh.y);
    o4.z = f2b((a.z - mean)*inv*gsc.z + gsh.z);
    o4.w = f2b((a.w - mean)*inv*gsc.w + gsh.w);
    reinterpret_cast<ushort4*>(hout + ((size_t)row << 10))[tid] = o4;
    return;
  }
  __shared__ u16 tile[64*68];
  const int which = bid >> 8, t = bid & 255;
  const float* W = (which == 0) ? wq : (which == 1) ? wk : (which == 2) ? wv : wo;
  u16* Wt = (which == 3) ? woT : wqkvT + (size_t)which * D_ * D_;
  wconv_tile(W, Wt, 1024, 1024, t >> 4, t & 15, tid, tile);
}

// ---------- split-K reduce (bf16 partials, +bias, + bf16 resid) -> fp32 out ----------
__global__ __launch_bounds__(256) void reduce2(const u16* __restrict__ p,
                                               const float* __restrict__ bias,
                                               const u16* __restrict__ resid,
                                               float* __restrict__ out){
  const size_t idx = ((size_t)blockIdx.x << 8) + threadIdx.x;      // 4-elem index
  ushort4 a4 = reinterpret_cast<const ushort4*>(p)[idx];
  ushort4 b4 = reinterpret_cast<const ushort4*>(p)[idx + (((size_t)M_*D_) >> 2)];
  ushort4 r4 = reinterpret_cast<const ushort4*>(resid)[idx];
  float4 bb = reinterpret_cast<const float4*>(bias)[threadIdx.x];
  float4 o;
  o.x = b2f(a4.x) + b2f(b4.x) + b2f(r4.x) + bb.x;
  o.y = b2f(a4.y) + b2f(b4.y) + b2f(r4.y) + bb.y;
  o.z = b2f(a4.z) + b2f(b4.z) + b2f(r4.z) + bb.z;
  o.w = b2f(a4.w) + b2f(b4.w) + b2f(r4.w) + bb.w;
  reinterpret_cast<float4*>(out)[idx] = o;
}

// ---------- fused: split-K reduce (+bo + fp32 resid x) -> x1 bf16 AND LN2 -> h2 bf16 ----------
__global__ __launch_bounds__(256) void reduce_ln(const u16* __restrict__ p,
                                                 const float* __restrict__ bias,
                                                 const float* __restrict__ resid,
                                                 const float* __restrict__ sc,
                                                 const float* __restrict__ sh,
                                                 u16* __restrict__ x1,
                                                 u16* __restrict__ h2){
  const int row = blockIdx.x;
  const int tid = threadIdx.x;
  const size_t idx = ((size_t)row << 8) + tid;
  ushort4 a4 = reinterpret_cast<const ushort4*>(p)[idx];
  ushort4 b4 = reinterpret_cast<const ushort4*>(p)[idx + (((size_t)M_*D_) >> 2)];
  float4 r  = reinterpret_cast<const float4*>(resid)[idx];
  float4 bb = reinterpret_cast<const float4*>(bias)[tid];
  float4 v;
  v.x = b2f(a4.x) + b2f(b4.x) + r.x + bb.x;
  v.y = b2f(a4.y) + b2f(b4.y) + r.y + bb.y;
  v.z = b2f(a4.z) + b2f(b4.z) + r.z + bb.z;
  v.w = b2f(a4.w) + b2f(b4.w) + r.w + bb.w;
  ushort4 xo;
  xo.x = f2b(v.x); xo.y = f2b(v.y); xo.z = f2b(v.z); xo.w = f2b(v.w);
  reinterpret_cast<ushort4*>(x1)[idx] = xo;
  float s = v.x + v.y + v.z + v.w;
  float q = v.x*v.x + v.y*v.y + v.z*v.z + v.w*v.w;
  #pragma unroll
  for (int o = 32; o > 0; o >>= 1){ s += __shfl_xor(s, o); q += __shfl_xor(q, o); }
  __shared__ float red[8];
  const int w = tid >> 6;
  if ((tid & 63) == 0){ red[w] = s; red[4 + w] = q; }
  __syncthreads();
  float S = red[0] + red[1] + red[2] + red[3];
  float Q = red[4] + red[5] + red[6] + red[7];
  float mean = S * (1.0f/1024.0f);
  float var  = Q * (1.0f/1024.0f) - mean*mean;
  float inv = rsqrtf(var + 1e-5f);
  float4 gsc = reinterpret_cast<const float4*>(sc)[tid];
  float4 gsh = reinterpret_cast<const float4*>(sh)[tid];
  ushort4 o4;
  o4.x = f2b((v.x - mean)*inv*gsc.x + gsh.x);
  o4.y = f2b((v.y - mean)*inv*gsc.y + gsh.y);
  o4.z = f2b((v.z - mean)*inv*gsc.z + gsh.z);
  o4.w = f2b((v.w - mean)*inv*gsc.w + gsh.w);
  reinterpret_cast<ushort4*>(h2 + ((size_t)row << 10))[tid] = o4;
}

// ---------- 4-merged-phase 256-wide bf16 GEMM (32 MFMA per barrier) ----------
// r21: relaxed counted-vmcnt ledger — WVX allows the just-issued B-stage to stay in
// flight (FIFO: the wait only proves the older A-stage landed). WVX = 8 (NF4) / 2 (NF2).
// EPI 0: bf16 partial (split-K via gridDim.z), 3D grid
// EPI 1: QKV, 1D grid: blocks [0,192) GEMM; blocks [192,1216) w1/w2 wconv fillers
// EPI 3: gelu_tanh(+bias) -> bf16
template<int EPI, int NF>
__global__ __launch_bounds__(512, 2) void gemm8(const u16* __restrict__ A, const u16* __restrict__ Bt,
                                                const float* __restrict__ bias,
                                                void* __restrict__ Cv, void* __restrict__ Cv2,
                                                const float* __restrict__ cw1,
                                                const float* __restrict__ cw2,
                                                u16* __restrict__ w1T, u16* __restrict__ w2T,
                                                int M, int N, int K, int lda){
  constexpr int BROWS = NF * 32;            // rows per B half-tile
  __shared__ __align__(16) u16 LA[2][2][128*64];
  __shared__ __align__(16) u16 LB[2][2][BROWS*64];
  const int tid = threadIdx.x;

  if constexpr (EPI == 1){
    if (blockIdx.x >= 192){                 // ---- w1/w2 conversion filler blocks ----
      const int tid256 = tid & 255, sel2 = tid >> 8;
      u16* tile = &LA[0][0][0] + sel2 * (64*68);
      const int t = ((int)blockIdx.x - 192)*2 + sel2;
      if (t < 1024) wconv_tile(cw1, w1T, 1024, 4096, t >> 6, t & 63, tid256, tile);
      else          wconv_tile(cw2, w2T, 4096, 1024, (t-1024) >> 4, (t-1024) & 15, tid256, tile);
      return;
    }
  }

  const int lane = tid & 63;
  const int w = tid >> 6;
  const int wm = w >> 2, wn = w & 3;
  const int g = lane >> 4, l15 = lane & 15;
  const int bnb = (wn & 1) * (NF * 16);     // B local row base within half (wn>>1)

  int tn, tm, kz;
  if constexpr (EPI == 1){                  // 1D grid, 192 gemm blocks
    const int flat = blockIdx.x;
    const int nfid = (flat & 7) * 24 + (flat >> 3);
    tn = nfid % 12; tm = nfid / 12; kz = 0;
  } else {
    const int nx = gridDim.x, ny = gridDim.y;
    const int nwg = nx * ny * gridDim.z;
    const int flat = blockIdx.x + nx * (blockIdx.y + ny * blockIdx.z);
    const int nfid = (flat & 7) * (nwg >> 3) + (flat >> 3);
    tn = nfid % nx;
    const int rest = nfid / nx;
    tm = rest % ny;
    kz = rest / ny;
  }
  const int tn0 = tn * (NF * 64);
  const int tm0 = tm << 8;
  const u16* Az = A  + (size_t)kz * K;
  const u16* Bz = Bt + (size_t)kz * K;

  const int arow0 = tid >> 3,         asl0 = (((tid) & 7) ^ (arow0 & 7)) << 3;
  const int arow1 = (tid + 512) >> 3, asl1 = (((tid + 512) & 7) ^ (arow1 & 7)) << 3;

  f32x4 acc[8][NF];
  #pragma unroll
  for (int i = 0; i < 8; i++)
    #pragma unroll
    for (int j = 0; j < NF; j++) acc[i][j] = (f32x4){0.f,0.f,0.f,0.f};
  s16x8 bf[NF][2];
  constexpr int WVX = (NF == 4) ? 8 : 2;    // relaxed exact-sufficiency (r21 ledger)

#define STG_A(db, h, tt) do{                                                        \
    gl_lds16(Az + (size_t)(tm0 + (h)*128 + arow0)*lda + ((tt) << 6) + asl0,         \
             &LA[db][h][tid*8]);                                                    \
    gl_lds16(Az + (size_t)(tm0 + (h)*128 + arow1)*lda + ((tt) << 6) + asl1,         \
             &LA[db][h][(tid + 512)*8]);                                            \
  }while(0)
#define STG_B(db, h, tt) do{                                                        \
    gl_lds16(Bz + (size_t)(tn0 + (h)*BROWS + arow0)*lda + ((tt) << 6) + asl0,       \
             &LB[db][h][tid*8]);                                                    \
    if constexpr (NF == 4){                                                         \
      gl_lds16(Bz + (size_t)(tn0 + (h)*BROWS + arow1)*lda + ((tt) << 6) + asl1,     \
               &LB[db][h][(tid + 512)*8]);                                          \
    }                                                                               \
  }while(0)
#define LDAF(db, mf, kk) (*reinterpret_cast<const s16x8*>(                          \
    &LA[db][wm][((mf)*16 + l15)*64 + ((((kk)*4 + g) ^ (l15 & 7)) << 3)]))
#define LDBF(db, nf, kk) (*reinterpret_cast<const s16x8*>(                          \
    &LB[db][wn >> 1][(bnb + (nf)*16 + l15)*64 + ((((kk)*4 + g) ^ (l15 & 7)) << 3)]))
#define BLOAD(db) do{ _Pragma("unroll")                                             \
    for (int nf = 0; nf < NF; nf++){ bf[nf][0] = LDBF(db, nf, 0);                   \
                                     bf[nf][1] = LDBF(db, nf, 1); } }while(0)
// merged phase: 8 A-frag ds_reads, stage clump, barrier, 32 MFMA, barrier
#define PH2(db, MF0, STG, WV) do{                                                   \
    s16x8 aA0 = LDAF(db, (MF0)+0, 0), aA1 = LDAF(db, (MF0)+0, 1);                   \
    s16x8 aB0 = LDAF(db, (MF0)+1, 0), aB1 = LDAF(db, (MF0)+1, 1);                   \
    s16x8 aC0 = LDAF(db, (MF0)+2, 0), aC1 = LDAF(db, (MF0)+2, 1);                   \
    s16x8 aD0 = LDAF(db, (MF0)+3, 0), aD1 = LDAF(db, (MF0)+3, 1);                   \
    STG;                                                                            \
    WV;                                                                             \
    __builtin_amdgcn_s_barrier();                                                   \
    __builtin_amdgcn_s_setprio(1);                                                  \
    _Pragma("unroll")                                                               \
    for (int nf = 0; nf < NF; nf++){                                                \
      acc[(MF0)+0][nf] = __builtin_amdgcn_mfma_f32_16x16x32_bf16(aA0, bf[nf][0], acc[(MF0)+0][nf], 0,0,0); \
      acc[(MF0)+0][nf] = __builtin_amdgcn_mfma_f32_16x16x32_bf16(aA1, bf[nf][1], acc[(MF0)+0][nf], 0,0,0); \
      acc[(MF0)+1][nf] = __builtin_amdgcn_mfma_f32_16x16x32_bf16(aB0, bf[nf][0], acc[(MF0)+1][nf], 0,0,0); \
      acc[(MF0)+1][nf] = __builtin_amdgcn_mfma_f32_16x16x32_bf16(aB1, bf[nf][1], acc[(MF0)+1][nf], 0,0,0); \
      acc[(MF0)+2][nf] = __builtin_amdgcn_mfma_f32_16x16x32_bf16(aC0, bf[nf][0], acc[(MF0)+2][nf], 0,0,0); \
      acc[(MF0)+2][nf] = __builtin_amdgcn_mfma_f32_16x16x32_bf16(aC1, bf[nf][1], acc[(MF0)+2][nf], 0,0,0); \
      acc[(MF0)+3][nf] = __builtin_amdgcn_mfma_f32_16x16x32_bf16(aD0, bf[nf][0], acc[(MF0)+3][nf], 0,0,0); \
      acc[(MF0)+3][nf] = __builtin_amdgcn_mfma_f32_16x16x32_bf16(aD1, bf[nf][1], acc[(MF0)+3][nf], 0,0,0); \
    }                                                                               \
    __builtin_amdgcn_s_setprio(0);                                                  \
    __builtin_amdgcn_s_barrier();                                                   \
  }while(0)

  const int NT = K >> 6;                     // even at every call site
  STG_B(0, 0, 0); STG_B(0, 1, 0); STG_A(0, 0, 0); STG_A(0, 1, 0);
  STG_B(1, 0, 1); STG_B(1, 1, 1);
  waitvm<WVX>();                             // B(0)+A(0) landed; B(1,1) may stay in flight
  __builtin_amdgcn_s_barrier();

  for (int t = 0; t < NT; t += 2){
    const bool last = (t + 2 >= NT);
    BLOAD(0);
    PH2(0, 0, { STG_A(1, 0, t + 1); STG_A(1, 1, t + 1); }, );
    PH2(0, 4, { if (!last){ STG_B(0, 0, t + 2); STG_B(0, 1, t + 2); } },
              if (last) waitvm<0>(); else waitvm<WVX>(););
    BLOAD(1);
    PH2(1, 0, { if (!last){ STG_A(0, 0, t + 2); STG_A(0, 1, t + 2); } }, );
    PH2(1, 4, { if (!last){ STG_B(1, 0, t + 3); STG_B(1, 1, t + 3); } },
              if (last) waitvm<0>(); else waitvm<WVX>(););
  }
#undef STG_A
#undef STG_B
#undef LDAF
#undef LDBF
#undef BLOAD
#undef PH2

  if constexpr (EPI == 1){
    const int sel = tn0 >> 10;                     // block-uniform: 256-col tiles
    if (sel < 2){                                  // ---- Q/K coalesced scatter ----
      #pragma unroll
      for (int mf = 0; mf < 8; mf++){
        const int mb = tm0 + wm*128 + mf*16 + (g << 2);
        #pragma unroll
        for (int nf = 0; nf < NF; nf++){
          const int n = tn0 + wn*(NF*16) + nf*16 + l15;
          const int nn = n & 1023;
          const int hh = nn >> 6, d = nn & 63;
          #pragma unroll
          for (int rr = 0; rr < 4; rr++){
            const int m = mb + rr;
            float v = acc[mf][nf][rr];
            if (sel == 0) v *= SC2F;
            ((u16*)Cv)[(size_t)sel*((size_t)M_*D_) +
                       ((((size_t)(m >> 11)*H_ + hh)*T_ + (m & 2047)) << 6) + d] = f2b(v);
          }
        }
      }
    } else {                                       // ---- V: LDS transpose -> V^T [B][H][HD][T] ----
      u16* TR = &LA[0][0][0];                      // 128 x 256 u16 view (64KB), XOR-swizzled
      u16* vt = (u16*)Cv2;
      const int bq = tm0 >> 11;                    // batch index
      const int tloc = tm0 & 2047;                 // within-batch t base
      #pragma unroll
      for (int hp = 0; hp < 2; hp++){
        __syncthreads();                           // prev LA use / prev hp reads done
        if ((wn >> 1) == hp){
          #pragma unroll
          for (int mf = 0; mf < 8; mf++){
            const int mb = wm*128 + mf*16 + (g << 2);
            #pragma unroll
            for (int nf = 0; nf < NF; nf++){
              const int nr = ((wn & 1) << 6) + (nf << 4) + l15;    // [0,128)
              #pragma unroll
              for (int rr = 0; rr < 4; rr++){
                const int m = mb + rr;
                TR[nr*256 + (((m >> 3) ^ (nr & 15)) << 3) + (m & 7)] = f2b(acc[mf][nf][rr]);
              }
            }
          }
        }
        __syncthreads();
        {
          const int nr = tid >> 2;                 // [0,128)
          const int m0 = (tid & 3) << 6;           // 64-elem run per thread
          const int nn = (tn0 & 1023) + (hp << 7) + nr;
          const int hh = nn >> 6, d = nn & 63;
          u16* dst = vt + (((size_t)(bq*H_ + hh))*HD_ + d)*T_ + tloc + m0;
          #pragma unroll
          for (int jj = 0; jj < 8; jj++){
            const int j = (m0 >> 3) + jj;
            s16x8 vv = *reinterpret_cast<const s16x8*>(&TR[nr*256 + ((j ^ (nr & 15)) << 3)]);
            *reinterpret_cast<s16x8*>(dst + jj*8) = vv;
          }
        }
      }
    }
  } else {
    #pragma unroll
    for (int mf = 0; mf < 8; mf++){
      const int mb = tm0 + wm*128 + mf*16 + (g << 2);
      #pragma unroll
      for (int nf = 0; nf < NF; nf++){
        const int n = tn0 + wn*(NF*16) + nf*16 + l15;
        #pragma unroll
        for (int rr = 0; rr < 4; rr++){
          const int m = mb + rr;
          float v = acc[mf][nf][rr];
          if constexpr (EPI == 0){
            ((u16*)Cv)[(size_t)kz*((size_t)M*N) + (size_t)m*N + n] = f2b(v);
          } else {
            float u = v + bias[n];
            float t2 = 0.7978845608f*(u + 0.044715f*u*u*u);
            float e = __expf(2.0f*t2);
            float th = 1.0f - 2.0f/(e + 1.0f);
            ((u16*)Cv)[(size_t)m*N + n] = f2b(0.5f*u*(1.0f + th));
          }
        }
      }
    }
  }
}

// ---------- causal flash attention, v11 (best measured): KVBLK=128, double-buffer ----------
__global__ __launch_bounds__(512) void attn_k(const u16* __restrict__ Qg, const u16* __restrict__ Kg,
                                              const u16* __restrict__ Vg, u16* __restrict__ ctx){
  const int flat = blockIdx.x + (blockIdx.y << 3);
  const int xcd = flat & 7, j_ = (flat >> 3) & 3, pr_ = flat >> 5;   // pr_ in [0,8)
  const int bh  = (j_ << 3) + xcd;
  const int tid = threadIdx.x;
  const int lane = tid & 63;
  const int w = tid >> 6;                         // 0..7, wave owns q rows [16w,16w+16)
  const int g = lane >> 4, l15 = lane & 15;

  __shared__ __align__(16) u16 Qs[128*64];
  __shared__ __align__(16) u16 Ks[2][128*64];     // [krow][d]
  __shared__ __align__(16) u16 Vt[2][64*128];     // [d][t]
  __shared__ __align__(16) u16 Pl[8][16*128];     // per-wave P [q][k], 16-chunk rows
  u16* const Plw = &Pl[w][0];

  const size_t hb = (size_t)bh * ((size_t)T_*HD_);
  const u16* Qh = Qg + hb;
  const u16* Kh = Kg + hb;
  const u16* Vh = Vg + hb;                        // transposed head: [64][2048]
  const int b = bh >> 4, hh = bh & 15;

  const int qk_r0 = tid >> 3,         qk_c0 = (((tid) & 7) ^ (qk_r0 & 7)) << 3;
  const int qk_r1 = (tid + 512) >> 3, qk_c1 = (((tid + 512) & 7) ^ (qk_r1 & 7)) << 3;
  const int v_r0 = tid >> 4,          v_c0 = (((tid) & 15) ^ (v_r0 & 7)) << 3;
  const int v_r1 = (tid + 512) >> 4,  v_c1 = (((tid + 512) & 15) ^ (v_r1 & 7)) << 3;

  for (int ph = 0; ph < 2; ++ph){
    const int qt = ph ? (15 - pr_) : pr_;
    const int NKT = qt + 1;

    gl_lds16(Qh + (size_t)(qt*128 + qk_r0)*HD_ + qk_c0, Qs + tid*8);
    gl_lds16(Qh + (size_t)(qt*128 + qk_r1)*HD_ + qk_c1, Qs + (tid+512)*8);
    gl_lds16(Kh + (size_t)qk_r0*HD_ + qk_c0, Ks[0] + tid*8);
    gl_lds16(Kh + (size_t)qk_r1*HD_ + qk_c1, Ks[0] + (tid+512)*8);
    gl_lds16(Vh + (size_t)v_r0*T_ + v_c0, Vt[0] + tid*8);
    gl_lds16(Vh + (size_t)v_r1*T_ + v_c1, Vt[0] + (tid+512)*8);
    __syncthreads();

    s16x8 qa[2];
    #pragma unroll
    for (int kk = 0; kk < 2; kk++){
      int ra = (w << 4) + l15;
      int slot = (kk << 2) + g;
      qa[kk] = *reinterpret_cast<const s16x8*>(Qs + ra*64 + ((slot ^ (ra & 7)) << 3));
    }

    f32x4 accO[4];
    #pragma unroll
    for (int j = 0; j < 4; j++) accO[j] = (f32x4){0.f,0.f,0.f,0.f};
    float mrow = -1e30f, lrow = 0.f;
    const int qgl = qt*128 + (w << 4) + l15;      // this thread's global q row

    for (int kt = 0; kt < NKT; ++kt){
      const int cur = kt & 1, nxt = cur ^ 1;
      const bool pf = (kt + 1 < NKT);

      if (pf){                                    // async prefetch tile kt+1 (K + V, 128-wide)
        gl_lds16(Kh + (size_t)((kt+1)*128 + qk_r0)*HD_ + qk_c0, Ks[nxt] + tid*8);
        gl_lds16(Kh + (size_t)((kt+1)*128 + qk_r1)*HD_ + qk_c1, Ks[nxt] + (tid+512)*8);
        gl_lds16(Vh + (size_t)v_r0*T_ + (kt+1)*128 + v_c0, Vt[nxt] + tid*8);
        gl_lds16(Vh + (size_t)v_r1*T_ + (kt+1)*128 + v_c1, Vt[nxt] + (tid+512)*8);
      }

      // ---- S^T = K Q^T (swapped operands): 8 k-frags of 16 rows
      f32x4 accS[8];
      #pragma unroll
      for (int j = 0; j < 8; j++) accS[j] = (f32x4){0.f,0.f,0.f,0.f};
      __builtin_amdgcn_s_setprio(1);
      #pragma unroll
      for (int jn = 0; jn < 8; jn++){
        #pragma unroll
        for (int kk = 0; kk < 2; kk++){
          int rb = (jn << 4) + l15;               // K row (k index) 0..127
          int slot = (kk << 2) + g;
          s16x8 kf = *reinterpret_cast<const s16x8*>(Ks[cur] + rb*64 + ((slot ^ (rb & 7)) << 3));
          accS[jn] = __builtin_amdgcn_mfma_f32_16x16x32_bf16(kf, qa[kk], accS[jn], 0, 0, 0);
        }
      }
      __builtin_amdgcn_s_setprio(0);

      // ---- causal mask in place (only the diagonal tile kt==qt masks)
      if (kt == qt){
        #pragma unroll
        for (int jn = 0; jn < 8; jn++)
          #pragma unroll
          for (int rr = 0; rr < 4; rr++){
            int kgl = kt*128 + (jn << 4) + (g << 2) + rr;
            if (kgl > qgl) accS[jn][rr] = -1e30f;
          }
      }

      // ---- row max over 32 values: register chain + 2 shuffles
      float rmax = accS[0][0];
      #pragma unroll
      for (int jn = 0; jn < 8; jn++)
        #pragma unroll
        for (int rr = 0; rr < 4; rr++) rmax = fmaxf(rmax, accS[jn][rr]);
      rmax = fmaxf(rmax, __shfl_xor(rmax, 16));
      rmax = fmaxf(rmax, __shfl_xor(rmax, 32));

      // ---- T13: rescale only when the running max grew by >8 (log2 domain)
      if (__any(rmax > mrow + 8.0f)){
        float mn = fmaxf(mrow, rmax);
        float sf = exp2f(mrow - mn);
        mrow = mn;
        lrow *= sf;
        #pragma unroll
        for (int rr = 0; rr < 4; rr++){
          float sfr = __shfl(sf, ((lane >> 4) << 2) + rr);
          #pragma unroll
          for (int jn = 0; jn < 4; jn++) accO[jn][rr] *= sfr;
        }
      }

      // ---- P = exp2(S^T - m): packed store to Plw [q=l15][k]
      float tsum = 0.f;
      #pragma unroll
      for (int jn = 0; jn < 8; jn++){
        float pv0 = exp2f(accS[jn][0] - mrow);
        float pv1 = exp2f(accS[jn][1] - mrow);
        float pv2 = exp2f(accS[jn][2] - mrow);
        float pv3 = exp2f(accS[jn][3] - mrow);
        tsum += (pv0 + pv1) + (pv2 + pv3);
        int ch = ((jn << 1) | (g >> 1)) ^ (l15 & 7);           // swizzled 16B-chunk
        int base = (l15 << 7) + (ch << 3) + ((g & 1) << 2);    // u16 index
        uint2 pkd = make_uint2(pk2(pv0, pv1), pk2(pv2, pv3));
        *reinterpret_cast<uint2*>(&Plw[base]) = pkd;
      }
      tsum += __shfl_xor(tsum, 16);
      tsum += __shfl_xor(tsum, 32);
      lrow += tsum;

      // ---- O += P V : 4 k-frags x 4 d-frags
      __builtin_amdgcn_s_setprio(1);
      #pragma unroll
      for (int kk = 0; kk < 4; kk++){
        int pch = ((kk << 2) + g) ^ (l15 & 7);                 // P A-frag chunk
        s16x8 pa = *reinterpret_cast<const s16x8*>(&Plw[(l15 << 7) + (pch << 3)]);
        #pragma unroll
        for (int jn = 0; jn < 4; jn++){
          int vd = (jn << 4) + l15;
          int vslot = (((kk << 2) + g) & 8) | ((((kk << 2) + g) ^ (vd & 7)) & 7);
          s16x8 vbf = *reinterpret_cast<const s16x8*>(Vt[cur] + (vd << 7) + (vslot << 3));
          accO[jn] = __builtin_amdgcn_mfma_f32_16x16x32_bf16(pa, vbf, accO[jn], 0, 0, 0);
        }
      }
      __builtin_amdgcn_s_setprio(0);

      __syncthreads();                            // drains prefetch; closes iteration
    }

    // ---- epilogue: registers + global only (no LDS)
    #pragma unroll
    for (int rr = 0; rr < 4; rr++){
      float lr = __shfl(lrow, ((lane >> 4) << 2) + rr);
      float inv = 1.0f / lr;
      int qrow = qt*128 + (w << 4) + (g << 2) + rr;
      size_t rowbase = ((size_t)(b*T_ + qrow) << 10) + ((size_t)hh << 6);
      #pragma unroll
      for (int jn = 0; jn < 4; jn++){
        int d = (jn << 4) + l15;
        ctx[rowbase + d] = f2b(accO[jn][rr] * inv);
      }
    }
  }
}

// ---------- launch ----------
extern "C" void kernel_launch(void* const* d_in, const int* in_sizes, int n_in,
                              void* d_out, int out_size, void* d_ws, size_t ws_size,
                              hipStream_t stream){
  (void)in_sizes; (void)n_in; (void)out_size; (void)ws_size;
  const float* x    = (const float*)d_in[0];
  const float* wq   = (const float*)d_in[1];
  const float* wk   = (const float*)d_in[2];
  const float* wv   = (const float*)d_in[3];
  const float* wo   = (const float*)d_in[4];
  const float* bo   = (const float*)d_in[5];
  const float* ln1s = (const float*)d_in[6];
  const float* ln1b = (const float*)d_in[7];
  const float* ln2s = (const float*)d_in[8];
  const float* ln2b = (const float*)d_in[9];
  const float* w1   = (const float*)d_in[10];
  const float* b1   = (const float*)d_in[11];
  const float* w2   = (const float*)d_in[12];
  const float* b2   = (const float*)d_in[13];
  float* out = (float*)d_out;

  char* p = (char*)d_ws;
  u16*  wqkvT = (u16*)p;  p += (size_t)3*D_*D_*2;
  u16*  woT   = (u16*)p;  p += (size_t)D_*D_*2;
  u16*  w1T   = (u16*)p;  p += (size_t)D_*DFF_*2;
  u16*  w2T   = (u16*)p;  p += (size_t)DFF_*D_*2;
  u16*  h     = (u16*)p;  p += (size_t)M_*D_*2;   // ln1 out; later part of split-K buf
  u16*  qb    = (u16*)p;  p += (size_t)M_*D_*2;   // q | k ([2][B][H][T][HD])
  u16*  kb    = (u16*)p;  p += (size_t)M_*D_*2;
  u16*  vb    = (u16*)p;  p += (size_t)M_*D_*2;   // unused
  u16*  ctx   = (u16*)p;  p += (size_t)M_*D_*2;
  u16*  x1    = (u16*)p;  p += (size_t)M_*D_*2;   // bf16 residual stream
  u16*  h2    = (u16*)p;  p += (size_t)M_*D_*2;
  u16*  ff1   = (u16*)p;  p += (size_t)M_*DFF_*2; // V^T home during QKV..attn; FFN1 out after
  (void)kb; (void)vb;
  u16* part = h;   // bf16 partials [2][M][1024] = 16MB over h+qb (Q dead when written)

  dim3 blk(256), blk8(512);
  wconv_all<<<1024 + M_, blk, 0, stream>>>(wq, wk, wv, wo, wqkvT, woT, x, ln1s, ln1b, h);
  gemm8<1,4><<<192 + 1024, blk8, 0, stream>>>(h, wqkvT, nullptr, qb, ff1,
                                              w1, w2, w1T, w2T, M_, 3*D_, D_, D_);
  attn_k<<<dim3(8,32), blk8, 0, stream>>>(qb, qb + (size_t)M_*D_, ff1, ctx);
  gemm8<0,2><<<dim3(8,16,2), blk8, 0, stream>>>(ctx, woT, nullptr, part, nullptr,
                                                nullptr, nullptr, nullptr, nullptr,
                                                M_, D_, D_/2, D_);
  reduce_ln<<<M_, blk, 0, stream>>>(part, bo, x, ln2s, ln2b, x1, h2);
  gemm8<3,4><<<dim3(16,16,1), blk8, 0, stream>>>(h2, w1T, b1, ff1, nullptr,
                                                 nullptr, nullptr, nullptr, nullptr,
                                                 M_, DFF_, D_, D_);
  gemm8<0,2><<<dim3(8,16,2), blk8, 0, stream>>>(ff1, w2T, nullptr, part, nullptr,
                                                nullptr, nullptr, nullptr, nullptr,
                                                M_, D_, DFF_/2, DFF_);
  reduce2<<<M_, blk, 0, stream>>>(part, b2, x1, out);
}